// Round 1
// baseline (1090.038 us; speedup 1.0000x reference)
//
#include <hip/hip_runtime.h>
#include <math.h>

#define TOK   16384
#define NF    2048
#define RANK_ 204
#define BK    16

// ---------------- K0: transpose W2 -> W2T (for coalesced masked-value dots) ----
__global__ __launch_bounds__(256) void k_transpose(const float* __restrict__ W2,
                                                   float* __restrict__ W2T){
  __shared__ float tile[32][33];
  int bm = blockIdx.x & 63, bc = blockIdx.x >> 6;
  int tx = threadIdx.x & 31, ty = threadIdx.x >> 5;
  int r0 = bm*32, c0 = bc*32;
#pragma unroll
  for(int i=0;i<4;i++) tile[ty+8*i][tx] = W2[(size_t)(r0+ty+8*i)*NF + c0+tx];
  __syncthreads();
#pragma unroll
  for(int i=0;i<4;i++) W2T[(size_t)(c0+ty+8*i)*NF + r0+tx] = tile[tx][ty+8*i];
}

// ---------------- K1: build sparse structure + masked attn values -------------
// colsT[e][o], valsT[e][o]  (transposed so K2 reads are lane-coalesced), e<32,
// padded with col=0,val=0.
__global__ __launch_bounds__(256) void k_setup(const float* __restrict__ mask,
                                               const float* __restrict__ W1,
                                               const float* __restrict__ W2T,
                                               int* __restrict__ colsT,
                                               float* __restrict__ valsT){
  int o = blockIdx.x;
  __shared__ float w1row[NF];
  __shared__ int scols[32];
  __shared__ int scnt;
  int tid = threadIdx.x;
  if(tid==0) scnt = 0;
  __syncthreads();
  // scan mask row o (values are exactly 0.0 / 1.0)
  for(int i=tid;i<NF;i+=256){
    if(mask[(size_t)o*NF+i] > 0.5f){
      int s = atomicAdd(&scnt,1);
      if(s<32) scols[s] = i;
    }
  }
  // stage W1 row o
  float4* w4 = (float4*)w1row;
  const float4* g4 = (const float4*)(W1 + (size_t)o*NF);
  w4[tid] = g4[tid]; w4[tid+256] = g4[tid+256];
  __syncthreads();
  int cnt = scnt; if(cnt>32) cnt=32;
  if(tid>=cnt && tid<32) scols[tid]=0;   // pad (val stays 0 below)
  __syncthreads();
  int wave = tid>>6, lane = tid&63;
  for(int e=wave; e<32; e+=4){
    float acc = 0.f;
    if(e<cnt){
      const float* wr = W2T + (size_t)scols[e]*NF;
#pragma unroll 8
      for(int j=0;j<32;j++) acc += w1row[lane+64*j]*wr[lane+64*j];
    }
#pragma unroll
    for(int off=32;off>0;off>>=1) acc += __shfl_down(acc, off, 64);
    if(lane==0) valsT[(size_t)e*NF+o] = acc;   // 0 for padded slots
  }
  if(tid<32) colsT[(size_t)tid*NF+o] = scols[tid];
}

// ---------------- K2: fused gate + sparse path: out = g * sparse --------------
__global__ __launch_bounds__(256) void k_sparse_gate(const float* __restrict__ x,
                                                     const float* __restrict__ gw,
                                                     const float* __restrict__ gb,
                                                     const int* __restrict__ colsT,
                                                     const float* __restrict__ valsT,
                                                     float* __restrict__ out,
                                                     float* __restrict__ g_ws){
  __shared__ float xs[6][NF];
  __shared__ float gwl[NF];
  __shared__ float sg[6];
  int tid = threadIdx.x;
  long t0 = (long)blockIdx.x*6;
  // stage 6 x-rows (vectorized, guarded) + gate weights
  float4* xs4 = (float4*)&xs[0][0];
#pragma unroll
  for(int l=0;l<12;l++){
    int idx = tid + 256*l;              // < 3072 float4s
    int row = idx>>9, c4 = idx&511;
    long t = t0 + row;
    float4 v = make_float4(0.f,0.f,0.f,0.f);
    if(t < TOK) v = ((const float4*)x)[t*512 + c4];
    xs4[idx] = v;
  }
  ((float4*)gwl)[tid]     = ((const float4*)gw)[tid];
  ((float4*)gwl)[tid+256] = ((const float4*)gw)[tid+256];
  __syncthreads();
  int wave = tid>>6, lane = tid&63;
  float gbv = gb[0];
  // gate per token (wave-parallel dot + reduce)
  for(int t=wave; t<6; t+=4){
    float s = 0.f;
#pragma unroll 8
    for(int j=0;j<32;j++) s += xs[t][lane+64*j]*gwl[lane+64*j];
#pragma unroll
    for(int off=32;off>0;off>>=1) s += __shfl_down(s, off, 64);
    if(lane==0) sg[t] = 1.f/(1.f+expf(-(s+gbv)));
  }
  __syncthreads();
  if(tid<6 && (t0+tid)<TOK) g_ws[t0+tid] = sg[tid];
  // sparse: lanes = outputs, 6 tokens in acc registers
  for(int ob = wave*512; ob < wave*512+512; ob += 64){
    int o = ob + lane;
    float acc[6] = {0.f,0.f,0.f,0.f,0.f,0.f};
    for(int e=0;e<32;e++){
      int   c = colsT[(size_t)e*NF+o];   // coalesced
      float v = valsT[(size_t)e*NF+o];   // coalesced
#pragma unroll
      for(int t=0;t<6;t++) acc[t] += xs[t][c]*v;
    }
#pragma unroll
    for(int t=0;t<6;t++){
      long tt = t0+t;
      if(tt<TOK) out[tt*(long)NF+o] = sg[t]*acc[t];
    }
  }
}

// ---------------- K3: T = X @ W2[:204]^T  (M=16384, N=204, K=2048) ------------
__global__ __launch_bounds__(256) void k_gemm1(const float* __restrict__ X,
                                               const float* __restrict__ W2,
                                               float* __restrict__ T){
  __shared__ alignas(16) float As[BK][132];
  __shared__ alignas(16) float Bs[BK][132];
  int bm = blockIdx.x & 127;
  int bn = blockIdx.x >> 7;            // 0..1
  int tid = threadIdx.x;
  int tx = tid & 15, ty = tid >> 4;
  int lrow = tid >> 2, lvec = tid & 3;
  long m0 = (long)bm*128; int n0 = bn*128;
  float acc[8][8];
#pragma unroll
  for(int i=0;i<8;i++)
#pragma unroll
    for(int j=0;j<8;j++) acc[i][j]=0.f;

  for(int kt=0; kt<NF/BK; ++kt){
    int k0 = kt*BK;
    float4 av[2], bv[2];
#pragma unroll
    for(int h=0;h<2;h++){
      long ar = m0 + lrow + 64*h;
      av[h] = ((const float4*)(X + ar*NF + k0))[lvec];
      int br = n0 + lrow + 64*h;
      bv[h] = make_float4(0.f,0.f,0.f,0.f);
      if(br < RANK_) bv[h] = ((const float4*)(W2 + (size_t)br*NF + k0))[lvec];
    }
    __syncthreads();
#pragma unroll
    for(int h=0;h<2;h++){
      int kk = lvec*4; int m = lrow+64*h;
      As[kk+0][m]=av[h].x; As[kk+1][m]=av[h].y; As[kk+2][m]=av[h].z; As[kk+3][m]=av[h].w;
      Bs[kk+0][m]=bv[h].x; Bs[kk+1][m]=bv[h].y; Bs[kk+2][m]=bv[h].z; Bs[kk+3][m]=bv[h].w;
    }
    __syncthreads();
#pragma unroll
    for(int kk=0;kk<BK;kk++){
      float am[8], bb[8];
      float4 a0 = *(const float4*)&As[kk][ty*4];
      float4 a1 = *(const float4*)&As[kk][ty*4+64];
      float4 b0 = *(const float4*)&Bs[kk][tx*4];
      float4 b1 = *(const float4*)&Bs[kk][tx*4+64];
      am[0]=a0.x;am[1]=a0.y;am[2]=a0.z;am[3]=a0.w;am[4]=a1.x;am[5]=a1.y;am[6]=a1.z;am[7]=a1.w;
      bb[0]=b0.x;bb[1]=b0.y;bb[2]=b0.z;bb[3]=b0.w;bb[4]=b1.x;bb[5]=b1.y;bb[6]=b1.z;bb[7]=b1.w;
#pragma unroll
      for(int i=0;i<8;i++)
#pragma unroll
        for(int j=0;j<8;j++) acc[i][j] += am[i]*bb[j];
    }
  }
#pragma unroll
  for(int ih=0; ih<2; ih++)
#pragma unroll
    for(int i=0;i<4;i++){
      long t = m0 + ty*4 + i + ih*64;
#pragma unroll
      for(int jh=0;jh<2;jh++){
        int n = n0 + tx*4 + jh*64;
        if(n < RANK_){   // 204 % 4 == 0, float4 never straddles
          float4 v = make_float4(acc[ih*4+i][jh*4+0], acc[ih*4+i][jh*4+1],
                                 acc[ih*4+i][jh*4+2], acc[ih*4+i][jh*4+3]);
          *(float4*)(T + t*RANK_ + n) = v;
        }
      }
    }
}

// ------- K4: out += (1-g) * (T @ W1[:, :204]^T) + bias  (M=16384,N=2048,K=204) -
__global__ __launch_bounds__(256) void k_gemm2(const float* __restrict__ T,
                                               const float* __restrict__ W1,
                                               const float* __restrict__ g_ws,
                                               const float* __restrict__ bias,
                                               float* __restrict__ out){
  __shared__ alignas(16) float As[BK][132];
  __shared__ alignas(16) float Bs[BK][132];
  __shared__ float gl[128];
  __shared__ float bl[128];
  int bm = blockIdx.x & 127;
  int bn = blockIdx.x >> 7;            // 0..15
  int tid = threadIdx.x;
  int tx = tid & 15, ty = tid >> 4;
  int lrow = tid >> 2, lvec = tid & 3;
  long m0 = (long)bm*128; int n0 = bn*128;
  if(tid<128){ gl[tid] = g_ws[m0+tid]; bl[tid] = bias[n0+tid]; }
  float acc[8][8];
#pragma unroll
  for(int i=0;i<8;i++)
#pragma unroll
    for(int j=0;j<8;j++) acc[i][j]=0.f;

  for(int kt=0; kt<13; ++kt){          // 13*16 >= 204, zero-padded
    int k0 = kt*BK;
    float4 av[2], bv[2];
#pragma unroll
    for(int h=0;h<2;h++){
      int kc = k0 + lvec*4;
      long ar = m0 + lrow + 64*h;
      int  br = n0 + lrow + 64*h;
      av[h] = make_float4(0.f,0.f,0.f,0.f);
      bv[h] = make_float4(0.f,0.f,0.f,0.f);
      if(kc < RANK_){                  // 204 % 4 == 0 -> kc<204 implies kc+3<204
        av[h] = *(const float4*)(T  + ar*RANK_ + kc);
        bv[h] = *(const float4*)(W1 + (size_t)br*NF + kc);
      }
    }
    __syncthreads();
#pragma unroll
    for(int h=0;h<2;h++){
      int kk = lvec*4; int m = lrow+64*h;
      As[kk+0][m]=av[h].x; As[kk+1][m]=av[h].y; As[kk+2][m]=av[h].z; As[kk+3][m]=av[h].w;
      Bs[kk+0][m]=bv[h].x; Bs[kk+1][m]=bv[h].y; Bs[kk+2][m]=bv[h].z; Bs[kk+3][m]=bv[h].w;
    }
    __syncthreads();
#pragma unroll
    for(int kk=0;kk<BK;kk++){
      float am[8], bb[8];
      float4 a0 = *(const float4*)&As[kk][ty*4];
      float4 a1 = *(const float4*)&As[kk][ty*4+64];
      float4 b0 = *(const float4*)&Bs[kk][tx*4];
      float4 b1 = *(const float4*)&Bs[kk][tx*4+64];
      am[0]=a0.x;am[1]=a0.y;am[2]=a0.z;am[3]=a0.w;am[4]=a1.x;am[5]=a1.y;am[6]=a1.z;am[7]=a1.w;
      bb[0]=b0.x;bb[1]=b0.y;bb[2]=b0.z;bb[3]=b0.w;bb[4]=b1.x;bb[5]=b1.y;bb[6]=b1.z;bb[7]=b1.w;
#pragma unroll
      for(int i=0;i<8;i++)
#pragma unroll
        for(int j=0;j<8;j++) acc[i][j] += am[i]*bb[j];
    }
  }
  // epilogue: out = g*sparse(prev) + (1-g)*lowrank + bias
#pragma unroll
  for(int ih=0; ih<2; ih++)
#pragma unroll
    for(int i=0;i<4;i++){
      int t_loc = ty*4 + i + ih*64;
      long t = m0 + t_loc;
      float gv = gl[t_loc];
      float om = 1.f - gv;
#pragma unroll
      for(int jh=0;jh<2;jh++){
        int n_loc = tx*4 + jh*64;
        long addr = t*(long)NF + n0 + n_loc;
        float4 prev = *(const float4*)(out + addr);
        float4 r;
        r.x = prev.x + om*acc[ih*4+i][jh*4+0] + bl[n_loc+0];
        r.y = prev.y + om*acc[ih*4+i][jh*4+1] + bl[n_loc+1];
        r.z = prev.z + om*acc[ih*4+i][jh*4+2] + bl[n_loc+2];
        r.w = prev.w + om*acc[ih*4+i][jh*4+3] + bl[n_loc+3];
        *(float4*)(out + addr) = r;
      }
    }
}

extern "C" void kernel_launch(void* const* d_in, const int* in_sizes, int n_in,
                              void* d_out, int out_size, void* d_ws, size_t ws_size,
                              hipStream_t stream) {
  const float* x    = (const float*)d_in[0];
  const float* W1   = (const float*)d_in[1];
  const float* W2   = (const float*)d_in[2];
  const float* gw   = (const float*)d_in[3];
  const float* gb   = (const float*)d_in[4];
  const float* bias = (const float*)d_in[5];
  const float* mask = (const float*)d_in[6];
  float* out = (float*)d_out;
  float* ws  = (float*)d_ws;

  // ws layout (floats). W2T region is reused as T after k_setup is done (stream-ordered).
  float* W2T   = ws;
  float* Tm    = ws;
  int*   colsT = (int*)(ws + (size_t)NF*NF);
  float* valsT = ws + (size_t)NF*NF + 32*(size_t)NF;
  float* g_ws  = ws + (size_t)NF*NF + 64*(size_t)NF;

  hipLaunchKernelGGL(k_transpose,   dim3(4096), dim3(256), 0, stream, W2, W2T);
  hipLaunchKernelGGL(k_setup,       dim3(2048), dim3(256), 0, stream, mask, W1, W2T, colsT, valsT);
  hipLaunchKernelGGL(k_sparse_gate, dim3((TOK+5)/6), dim3(256), 0, stream, x, gw, gb, colsT, valsT, out, g_ws);
  hipLaunchKernelGGL(k_gemm1,       dim3(256),  dim3(256), 0, stream, x, W2, Tm);
  hipLaunchKernelGGL(k_gemm2,       dim3(2048), dim3(256), 0, stream, Tm, W1, g_ws, bias, out);
}

// Round 2
// 701.397 us; speedup vs baseline: 1.5541x; 1.5541x over previous
//
#include <hip/hip_runtime.h>
#include <math.h>

#define TOK  16384
#define NF   2048
#define NGRP 342          // ceil(2048/6)
#define KPAD 224          // padded rank 204 -> 7*32
#define SGRP 24           // groups per sparse pass

typedef __attribute__((ext_vector_type(8))) short short8;
typedef __attribute__((ext_vector_type(4))) float f32x4;

__device__ __forceinline__ unsigned short f2bf(float f){
  unsigned u = __float_as_uint(f);
  return (unsigned short)((u + 0x7FFFu + ((u>>16)&1u)) >> 16);  // RTN-even
}
__device__ __forceinline__ float bf2f(unsigned short h){
  return __uint_as_float(((unsigned)h)<<16);
}

// ---- K0: x -> xT (bf16, [c][t]) + gate partial dots --------------------------
__global__ __launch_bounds__(256) void k_prep(const float* __restrict__ x,
                                              const float* __restrict__ gw,
                                              unsigned short* __restrict__ xT,
                                              float* __restrict__ gacc){
  __shared__ float s[64][65];
  __shared__ float gwl[64];
  int tid = threadIdx.x;
  int bt = blockIdx.x >> 5, bc = blockIdx.x & 31;
  long t0 = (long)bt*64; int c0 = bc*64;
  if(tid<64) gwl[tid] = gw[c0+tid];
  __syncthreads();
  int tr = tid>>2, q = tid&3;
  float gp = 0.f;
  const float* xrow = x + (t0+tr)*NF + c0 + q*16;
#pragma unroll
  for(int i=0;i<4;i++){
    float4 v = *(const float4*)(xrow + i*4);
    int c = q*16 + i*4;
    s[tr][c+0]=v.x; s[tr][c+1]=v.y; s[tr][c+2]=v.z; s[tr][c+3]=v.w;
    gp += v.x*gwl[c] + v.y*gwl[c+1] + v.z*gwl[c+2] + v.w*gwl[c+3];
  }
  gp += __shfl_down(gp, 2, 4);
  gp += __shfl_down(gp, 1, 4);
  if(q==0) atomicAdd(&gacc[t0+tr], gp);
  __syncthreads();
#pragma unroll
  for(int p=0;p<16;p++){
    int c = p*4 + (tid>>6);
    int t = tid&63;
    xT[(size_t)(c0+c)*TOK + t0 + t] = f2bf(s[t][c]);
  }
}

// ---- K1: W2 -> W2T (fp32) ----------------------------------------------------
__global__ __launch_bounds__(256) void k_transpose(const float* __restrict__ W2,
                                                   float* __restrict__ W2T){
  __shared__ float tile[32][33];
  int bm = blockIdx.x & 63, bc = blockIdx.x >> 6;
  int tx = threadIdx.x & 31, ty = threadIdx.x >> 5;
  int r0 = bm*32, c0 = bc*32;
#pragma unroll
  for(int i=0;i<4;i++) tile[ty+8*i][tx] = W2[(size_t)(r0+ty+8*i)*NF + c0+tx];
  __syncthreads();
#pragma unroll
  for(int i=0;i<4;i++) W2T[(size_t)(c0+ty+8*i)*NF + r0+tx] = tile[tx][ty+8*i];
}

// ---- K2: W1[:, :204] -> bf16 [2048][224] (zero-padded) -----------------------
__global__ __launch_bounds__(256) void k_wconv(const float* __restrict__ W1,
                                               unsigned short* __restrict__ w1b){
  int n = blockIdx.x, k = threadIdx.x;
  if(k < KPAD)
    w1b[(size_t)n*KPAD + k] = (k < 204) ? f2bf(W1[(size_t)n*NF + k]) : (unsigned short)0;
}

// ---- band structure of the stripe mask ---------------------------------------
// bands per output o: k0..k2 base 6*floor(o/6)+{0,45,90}; k3 base 6*floor((o-45)/6)
// (o>=45; splits mid-group since 45%6!=0); k4 base 6*floor((o-90)/6) (o>=90, uniform).
__device__ __forceinline__ void band_bases(int o, int* base, int* valid){
  int g6 = (o/6)*6;
  base[0]=g6;     valid[0]=1;
  base[1]=g6+45;  valid[1]=1;
  base[2]=g6+90;  valid[2]=1;
  base[3]=(o>=45)? ((o-45)/6)*6 : 0; valid[3]=(o>=45);
  base[4]=(o>=90)? ((o-90)/6)*6 : 0; valid[4]=(o>=90);
}

// ---- K3: V[o][32] = masked (W1@W2)[o][band cols] -----------------------------
__global__ __launch_bounds__(256) void k_setup(const float* __restrict__ mask,
                                               const float* __restrict__ W1,
                                               const float* __restrict__ W2T,
                                               float* __restrict__ V){
  int o = blockIdx.x;
  __shared__ float w1row[NF];
  int tid = threadIdx.x;
  float4* w4 = (float4*)w1row;
  const float4* g4 = (const float4*)(W1 + (size_t)o*NF);
  w4[tid] = g4[tid]; w4[tid+256] = g4[tid+256];
  __syncthreads();
  int wave = tid>>6, lane = tid&63;
  int base[5], valid[5];
  band_bases(o, base, valid);
  for(int slot = wave; slot < 32; slot += 4){
    int k = slot/6, e = slot - k*6;
    float acc = 0.f;
    if(k<5 && valid[k]){
      int c = base[k]+e;
      if(c < NF && mask[(size_t)o*NF + c] > 0.5f){
        const float* wr = W2T + (size_t)c*NF;
#pragma unroll 8
        for(int j=0;j<32;j++) acc += w1row[lane+64*j]*wr[lane+64*j];
      }
    }
#pragma unroll
    for(int off=32;off>0;off>>=1) acc += __shfl_down(acc, off, 64);
    if(lane==0) V[(size_t)o*32 + slot] = acc;
  }
}

// ---- K4: out = g * sparse ----------------------------------------------------
__device__ __forceinline__ float ldx(const unsigned short* __restrict__ xT, int c, long t){
  c = c < 0 ? 0 : (c > NF-1 ? NF-1 : c);   // clamped loads pair with V==0
  return bf2f(xT[(size_t)c*TOK + t]);
}

__global__ __launch_bounds__(256) void k_sparse(const unsigned short* __restrict__ xT,
                                                const float* __restrict__ V,
                                                const float* __restrict__ gacc,
                                                const float* __restrict__ gb,
                                                float* __restrict__ out){
  __shared__ float stage[64][145];   // stride 145: gcd(145%32=17,32)=1 -> 2-way max
  int tid = threadIdx.x;
  int bt = blockIdx.x >> 2, bo = blockIdx.x & 3;
  long t0 = (long)bt*64;
  int gbeg = bo*86, gend = min(gbeg+86, NGRP);
  int wave = tid>>6, lane = tid&63;
  long t = t0 + lane;
  float g = 1.f/(1.f + expf(-(gacc[t] + gb[0])));
  for(int p0 = gbeg; p0 < gend; p0 += SGRP){
    int pcnt = min(SGRP, gend - p0);
    int glim = min(wave*6+6, pcnt);
    for(int gi = wave*6; gi < glim; ++gi){
      int gid = p0 + gi;
      int cb0 = 6*gid, cb1 = 6*gid+45, cb2 = 6*gid+90, cb3 = 6*gid-48, cb4 = 6*gid-90;
      float xv[36];
#pragma unroll
      for(int e=0;e<6;e++){
        xv[e]    = ldx(xT, cb0+e, t);
        xv[6+e]  = ldx(xT, cb1+e, t);
        xv[12+e] = ldx(xT, cb2+e, t);
        xv[30+e] = ldx(xT, cb4+e, t);
      }
#pragma unroll
      for(int e=0;e<12;e++) xv[18+e] = ldx(xT, cb3+e, t);
#pragma unroll
      for(int j=0;j<6;j++){
        int o = cb0 + j;
        if(o >= NF) break;                 // only group 341
        const float* vr = V + (size_t)o*32;  // wave-uniform -> scalar loads
        float a = 0.f;
        int off = (j<3)?0:6;               // k3 half-band select (45%6==3)
#pragma unroll
        for(int e=0;e<6;e++){
          a += vr[e]    * xv[e];
          a += vr[6+e]  * xv[6+e];
          a += vr[12+e] * xv[12+e];
          a += vr[18+e] * xv[18+off+e];
          a += vr[24+e] * xv[30+e];
        }
        stage[lane][gi*6+j] = g*a;
      }
    }
    __syncthreads();
    int ocols = pcnt*6, obase = p0*6;
    if(tid < ocols){
      for(int tt=0; tt<64; ++tt){
        int o = obase + tid;
        if(o < NF) out[(t0+tt)*NF + o] = stage[tt][tid];
      }
    }
    __syncthreads();
  }
}

// ---- K5/K6: bf16 MFMA GEMM, 128x128 tile, BK=32, 4 waves ---------------------
// SRC_BF=0: A,B fp32 sources converted in staging. EPI=1: store bf16 C (T).
// EPI=2: out = out + (1-g)*acc + bias (RMW after sparse).
template<int SRC_BF, int EPI>
__global__ __launch_bounds__(256) void k_gemm(const void* __restrict__ Ap, int lda,
                                              const void* __restrict__ Bp, int ldb,
                                              int nBvalid, int K, int nshift,
                                              unsigned short* __restrict__ Cbf,
                                              float* __restrict__ out,
                                              const float* __restrict__ gacc,
                                              const float* __restrict__ gb,
                                              const float* __restrict__ bias){
  __shared__ unsigned short As[128*56];  // stride 56 (112B): 2-way max on b128
  __shared__ unsigned short Bs[128*56];
  __shared__ float gl[128], bl[128];
  int tid = threadIdx.x;
  int bm = blockIdx.x >> nshift;
  int bn = blockIdx.x & ((1<<nshift)-1);
  long m0 = (long)bm*128; int n0 = bn*128;
  if(EPI==2 && tid<128){
    gl[tid] = 1.f/(1.f+expf(-(gacc[m0+tid]+gb[0])));
    bl[tid] = bias[n0+tid];
  }
  f32x4 acc[4][4];
#pragma unroll
  for(int i=0;i<4;i++)
#pragma unroll
    for(int j=0;j<4;j++){ acc[i][j][0]=0.f; acc[i][j][1]=0.f; acc[i][j][2]=0.f; acc[i][j][3]=0.f; }

  int row = tid>>2, cg = tid&3;
  int wid = tid>>6, l = tid&63;
  int wm = wid>>1, wn = wid&1;
  int lr = l&15, lk = (l>>4)*8;

  for(int k0=0; k0<K; k0+=32){
#pragma unroll
    for(int h=0; h<2; h++){
      int r = row + 64*h;
      uint4 av, bv;
      if(SRC_BF){
        av = *(const uint4*)((const unsigned short*)Ap + (m0+r)*(size_t)lda + k0 + cg*8);
        if(n0+r < nBvalid)
          bv = *(const uint4*)((const unsigned short*)Bp + (size_t)(n0+r)*ldb + k0 + cg*8);
        else bv = make_uint4(0,0,0,0);
      } else {
        const float* af = (const float*)Ap + (m0+r)*(size_t)lda + k0 + cg*8;
        float4 a0 = *(const float4*)af, a1 = *(const float4*)(af+4);
        av.x = (unsigned)f2bf(a0.x) | ((unsigned)f2bf(a0.y)<<16);
        av.y = (unsigned)f2bf(a0.z) | ((unsigned)f2bf(a0.w)<<16);
        av.z = (unsigned)f2bf(a1.x) | ((unsigned)f2bf(a1.y)<<16);
        av.w = (unsigned)f2bf(a1.z) | ((unsigned)f2bf(a1.w)<<16);
        if(n0+r < nBvalid){
          const float* bf = (const float*)Bp + (size_t)(n0+r)*ldb + k0 + cg*8;
          float4 b0 = *(const float4*)bf, b1 = *(const float4*)(bf+4);
          bv.x = (unsigned)f2bf(b0.x) | ((unsigned)f2bf(b0.y)<<16);
          bv.y = (unsigned)f2bf(b0.z) | ((unsigned)f2bf(b0.w)<<16);
          bv.z = (unsigned)f2bf(b1.x) | ((unsigned)f2bf(b1.y)<<16);
          bv.w = (unsigned)f2bf(b1.z) | ((unsigned)f2bf(b1.w)<<16);
        } else bv = make_uint4(0,0,0,0);
      }
      *(uint4*)&As[r*56 + cg*8] = av;
      *(uint4*)&Bs[r*56 + cg*8] = bv;
    }
    __syncthreads();
    short8 a[4], b[4];
#pragma unroll
    for(int f=0; f<4; f++){
      a[f] = *(const short8*)&As[(wm*64 + f*16 + lr)*56 + lk];
      b[f] = *(const short8*)&Bs[(wn*64 + f*16 + lr)*56 + lk];
    }
#pragma unroll
    for(int i=0;i<4;i++)
#pragma unroll
      for(int j=0;j<4;j++)
        acc[i][j] = __builtin_amdgcn_mfma_f32_16x16x32_bf16(a[i], b[j], acc[i][j], 0,0,0);
    __syncthreads();
  }

#pragma unroll
  for(int i=0;i<4;i++)
#pragma unroll
    for(int j=0;j<4;j++)
#pragma unroll
      for(int r=0;r<4;r++){
        long m = m0 + wm*64 + i*16 + (l>>4)*4 + r;
        int nn = n0 + wn*64 + j*16 + lr;
        float v = acc[i][j][r];
        if(EPI==1){
          if(nn < KPAD) Cbf[m*KPAD + nn] = f2bf(v);
        } else {
          float prev = out[m*(size_t)NF + nn];
          out[m*(size_t)NF + nn] = prev + (1.f - gl[(int)(m-m0)])*v + bl[nn-n0];
        }
      }
}

extern "C" void kernel_launch(void* const* d_in, const int* in_sizes, int n_in,
                              void* d_out, int out_size, void* d_ws, size_t ws_size,
                              hipStream_t stream) {
  const float* x    = (const float*)d_in[0];
  const float* W1   = (const float*)d_in[1];
  const float* W2   = (const float*)d_in[2];
  const float* gw   = (const float*)d_in[3];
  const float* gb   = (const float*)d_in[4];
  const float* bias = (const float*)d_in[5];
  const float* mask = (const float*)d_in[6];
  float* out = (float*)d_out;
  char* ws = (char*)d_ws;

  // ws layout (~85 MB). W2T (16 MB) is dead after k_setup; T_bf aliases it.
  float*          W2T = (float*)ws;
  unsigned short* Tbf = (unsigned short*)ws;
  size_t off = (size_t)NF*NF*4;
  float* V    = (float*)(ws + off); off += (size_t)NF*32*4;
  float* gacc = (float*)(ws + off); off += (size_t)TOK*4;
  unsigned short* w1b = (unsigned short*)(ws + off); off += (size_t)NF*KPAD*2;
  unsigned short* xT  = (unsigned short*)(ws + off);

  hipMemsetAsync(gacc, 0, (size_t)TOK*4, stream);
  hipLaunchKernelGGL(k_prep,      dim3(8192), dim3(256), 0, stream, x, gw, xT, gacc);
  hipLaunchKernelGGL(k_transpose, dim3(4096), dim3(256), 0, stream, W2, W2T);
  hipLaunchKernelGGL(k_wconv,     dim3(2048), dim3(256), 0, stream, W1, w1b);
  hipLaunchKernelGGL(k_setup,     dim3(2048), dim3(256), 0, stream, mask, W1, W2T, V);
  hipLaunchKernelGGL(k_sparse,    dim3(1024), dim3(256), 0, stream, xT, V, gacc, gb, out);
  hipLaunchKernelGGL((k_gemm<0,1>), dim3(256),  dim3(256), 0, stream,
                     x, NF, W2, NF, 204, NF, 1, Tbf, nullptr, nullptr, nullptr, nullptr);
  hipLaunchKernelGGL((k_gemm<1,2>), dim3(2048), dim3(256), 0, stream,
                     Tbf, KPAD, w1b, KPAD, NF, KPAD, 4, nullptr, out, gacc, gb, bias);
}